// Round 6
// baseline (247.469 us; speedup 1.0000x reference)
//
#include <hip/hip_runtime.h>
#include <math.h>

// Problem constants
//  B=64, CH=64, T_IN=32, N_OSC=32, BAND=16384, N_NOISE_FRAMES=4096, NOISE_STEP=4
//  N_UP=7, LOWEST_FREQ = 20/11025
#define LOWEST_FREQ_F 0.00181405895691609977f

typedef short bf16x8 __attribute__((ext_vector_type(8)));
typedef float f32x16 __attribute__((ext_vector_type(16)));

__device__ __forceinline__ float lrelu(float x) { return x > 0.f ? x : 0.2f * x; }
__device__ __forceinline__ float sin_rev(float fr) { return __builtin_amdgcn_sinf(fr); }
__device__ __forceinline__ float bf2f(unsigned short u) {
  union { unsigned int i; float f; } x; x.i = ((unsigned int)u) << 16; return x.f;
}
__device__ __forceinline__ unsigned short f2bf(float f) {
  union { float f; unsigned int i; } x; x.f = f;
  unsigned int r = x.i + 0x7FFFu + ((x.i >> 16) & 1u);   // RNE
  return (unsigned short)(r >> 16);
}
__device__ __forceinline__ unsigned int pack2(float a, float b) {
  return (unsigned int)f2bf(a) | ((unsigned int)f2bf(b) << 16);
}

// ---------------------------------------------------------------------------
// z_front: one block per batch (64 blocks x 512 threads).
//  - writes its slice of wfold (folded noise conv weights, bf16)
//  - f32 conv stack: 2 waves compute (thread = co x 16-sample half); weights
//    staged as padded float4 [ci][co][4], register-double-buffered prefetch
//  - projections: 1 wave, o-column layout (aw/fw read once per c for 16 t)
//  - fp64 phase boundary prefix -> ph table
//  - y0 = nz_init via bf16 MFMA (waves 2-3 ONLY: tid in [128,256)) -> y0g
// ---------------------------------------------------------------------------
__global__ __launch_bounds__(512) void z_front(
    const float* __restrict__ x,
    const float* __restrict__ net_w, const float* __restrict__ net_b,
    const float* __restrict__ fin_w, const float* __restrict__ fin_b,
    const float* __restrict__ amp_w, const float* __restrict__ amp_b,
    const float* __restrict__ frq_w, const float* __restrict__ frq_b,
    const float* __restrict__ nzi_w, const float* __restrict__ nzi_b,
    const float* __restrict__ nzu_w,
    unsigned short* __restrict__ y0g, short* __restrict__ wfold,
    float* __restrict__ amp_o, float* __restrict__ frq_o,
    float* __restrict__ ph_o)
{
  __shared__ __align__(16) float wbuf4[64*64*4];   // 64 KB, [ci][co][4]
  __shared__ __align__(16) float za[64*36];        // rows ci, slot = t+1
  __shared__ __align__(16) float zb[64*36];
  __shared__ float awL[64*33];                     // [c][o], stride 33
  __shared__ float fwL[64*33];
  __shared__ float fl[32*33];                      // freq [o][t]
  __shared__ __align__(16) short zTb[32*72];       // bf16 z [t][c]

  const int b   = blockIdx.x;
  const int tid = threadIdx.x;

  // ---- wfold slice (independent; mid kernel consumes after we finish) ----
  for (int i = tid; i < 1792; i += 512) {
    int g = b * 1792 + i;
    int l = g >> 14, q = g & 16383;
    int pd = q >> 12, co = (q >> 6) & 63, ci = q & 63;
    const float* wb = nzu_w + l * 12288 + co * 192 + ci * 3;
    float v;
    if      (pd == 0) v = wb[0];
    else if (pd == 1) v = wb[1] + wb[2];
    else if (pd == 2) v = wb[0] + wb[1];
    else              v = wb[2];
    wfold[g] = (short)f2bf(v);
  }

  // ---- stage input + small tables ----
  for (int idx = tid; idx < 2048; idx += 512) {
    int t = idx >> 6, c = idx & 63;
    za[c*36 + t + 1] = x[b*2048 + idx];
  }
  if (tid < 64) {
    za[tid*36] = 0.f; za[tid*36 + 33] = 0.f;
    zb[tid*36] = 0.f; zb[tid*36 + 33] = 0.f;
  }
  for (int idx = tid; idx < 2048; idx += 512) {
    int c = idx >> 5, o = idx & 31;
    awL[c*33 + o] = amp_w[o*64 + c];
    fwL[c*33 + o] = frq_w[o*64 + c];
  }

  // ---- layer-0 weights to registers then LDS ----
  float pr[24];
  #pragma unroll
  for (int k = 0; k < 8; ++k) {
    int idx = tid + 512*k;
    int ci = idx >> 6, co = idx & 63;
    const float* p = net_w + co*192 + ci*3;
    pr[3*k+0] = p[0]; pr[3*k+1] = p[1]; pr[3*k+2] = p[2];
  }
  #pragma unroll
  for (int k = 0; k < 8; ++k)
    ((float4*)wbuf4)[tid + 512*k] = make_float4(pr[3*k], pr[3*k+1], pr[3*k+2], 0.f);
  __syncthreads();

  float* pa = za;
  float* pb = zb;
  for (int l = 0; l < 5; ++l) {
    if (l < 4) {   // prefetch next layer's weights into registers
      const float* src = (l+1 < 4) ? (net_w + (l+1)*12288) : fin_w;
      #pragma unroll
      for (int k = 0; k < 8; ++k) {
        int idx = tid + 512*k;
        int ci = idx >> 6, co = idx & 63;
        const float* p = src + co*192 + ci*3;
        pr[3*k+0] = p[0]; pr[3*k+1] = p[1]; pr[3*k+2] = p[2];
      }
    }
    if (tid < 128) {     // 2 waves compute the conv
      const int co = tid & 63;
      const int h  = (tid >> 6) & 1;
      float acc[16];
      {
        float bv = (l < 4) ? net_b[l*64 + co] : fin_b[co];
        #pragma unroll
        for (int j = 0; j < 16; ++j) acc[j] = bv;
      }
      #pragma unroll 2
      for (int ci = 0; ci < 64; ++ci) {
        float4 wv = ((const float4*)wbuf4)[ci*64 + co];
        const float* row = pa + ci*36 + 16*h;
        float r[20];
        #pragma unroll
        for (int i = 0; i < 5; ++i) {
          float4 v = *(const float4*)(row + 4*i);
          r[4*i+0]=v.x; r[4*i+1]=v.y; r[4*i+2]=v.z; r[4*i+3]=v.w;
        }
        #pragma unroll
        for (int j = 0; j < 16; ++j) {
          acc[j] = fmaf(wv.x, r[j],   acc[j]);
          acc[j] = fmaf(wv.y, r[j+1], acc[j]);
          acc[j] = fmaf(wv.z, r[j+2], acc[j]);
        }
      }
      const bool act = (l < 4);
      #pragma unroll
      for (int j = 0; j < 16; ++j) {
        float v = acc[j];
        pb[co*36 + 16*h + j + 1] = act ? lrelu(v) : v;
      }
    }
    __syncthreads();
    if (l < 4) {
      #pragma unroll
      for (int k = 0; k < 8; ++k)
        ((float4*)wbuf4)[tid + 512*k] = make_float4(pr[3*k], pr[3*k+1], pr[3*k+2], 0.f);
      __syncthreads();
    }
    float* tp = pa; pa = pb; pb = tp;
  }
  const float* zf = pa;   // final z, 64 ch x 32 t (+pads)

  // ---- bf16 transpose zTb[t][c] for the y0 MFMA ----
  for (int idx = tid; idx < 2048; idx += 512) {
    int t = idx & 31, c = idx >> 5;
    zTb[t*72 + c] = (short)f2bf(zf[c*36 + t + 1]);
  }
  __syncthreads();

  if (tid < 64) {
    // ---- projections: o-column, 16 t per thread ----
    const int o = tid & 31;
    const int h = tid >> 5;
    float aa[16], ff[16];
    {
      float ab = amp_b[o], fb = frq_b[o];
      #pragma unroll
      for (int j = 0; j < 16; ++j) { aa[j] = ab; ff[j] = fb; }
    }
    for (int c = 0; c < 64; ++c) {
      float wa = awL[c*33 + o];
      float wf_ = fwL[c*33 + o];
      const float* zr = zf + c*36 + 16*h + 1;
      #pragma unroll
      for (int j = 0; j < 16; ++j) {
        aa[j] = fmaf(wa,  zr[j], aa[j]);
        ff[j] = fmaf(wf_, zr[j], ff[j]);
      }
    }
    #pragma unroll
    for (int j = 0; j < 16; ++j) {
      int t = 16*h + j;
      float av = fabsf(aa[j]);
      float sg = 1.f / (1.f + expf(-ff[j]));
      float fq = LOWEST_FREQ_F + sg * (1.f - LOWEST_FREQ_F);
      amp_o[b*1024 + o*32 + t] = av;
      frq_o[b*1024 + o*32 + t] = fq;
      fl[o*33 + t] = fq;
    }
    // ---- fp64 phase boundary prefix (same-wave DS ordering is safe) ----
    if (tid < 32) {
      const int oo = tid;
      double P = 256.0 * (double)fl[oo*33];
      double hh = P * 0.5;
      ph_o[b*1024 + oo*32] = (float)(hh - floor(hh));
      for (int i = 1; i < 32; ++i) {
        P += 256.0 * ((double)fl[oo*33 + i - 1] + (double)fl[oo*33 + i]);
        hh = P * 0.5;
        ph_o[b*1024 + oo*32 + i] = (float)(hh - floor(hh));
      }
    }
  } else if (tid >= 128 && tid < 256) {
    // ---- y0 = nz_init via MFMA (bf16), waves 2-3 only -> mt in {0,1} ----
    const int L  = tid & 63;
    const int mt = (tid >> 6) - 2;    // 0 or 1
    bf16x8 Af[4];
    {
      const int row = mt*32 + (L & 31);
      const int kb  = (L >> 5) << 3;
      #pragma unroll
      for (int ks = 0; ks < 4; ++ks) {
        bf16x8 t8;
        #pragma unroll
        for (int jj = 0; jj < 8; ++jj)
          t8[jj] = (short)f2bf(nzi_w[row*64 + kb + ks*16 + jj]);
        Af[ks] = t8;
      }
    }
    f32x16 C;
    #pragma unroll
    for (int r = 0; r < 16; ++r)
      C[r] = nzi_b[mt*32 + (r & 3) + 8*(r >> 2) + 4*(L >> 5)];
    const short* bp = zTb + (L & 31)*72 + ((L >> 5) << 3);
    #pragma unroll
    for (int ks = 0; ks < 4; ++ks) {
      bf16x8 Bv = *(const bf16x8*)(bp + ks*16);
      C = __builtin_amdgcn_mfma_f32_32x32x16_bf16(Af[ks], Bv, C, 0, 0, 0);
    }
    const int t = L & 31;
    unsigned int* outw = (unsigned int*)y0g;
    #pragma unroll
    for (int q4 = 0; q4 < 4; ++q4) {
      int co0 = mt*32 + 8*q4 + 4*(L >> 5);
      uint2 v;
      v.x = pack2(C[4*q4+0], C[4*q4+1]);
      v.y = pack2(C[4*q4+2], C[4*q4+3]);
      *(uint2*)(outw + (((b*32 + t)*64 + co0) >> 1)) = v;
    }
  }
}

// ---------------------------------------------------------------------------
// mega-mid: noise layers 1..7 with halo recompute + full epilogue.
// Grid (16, 64): block = (t-chunk j, batch b); covers y7 frames [256j,256j+256)
// i.e. output samples [1024j, 1024j+1024).
// Windows (samples): y_l out [alpha_l, alpha_l + N_l):
//   l=1..6: alpha = (1<<(l+1))*j - 2, Ns = 2 + (1<<l), N = 2*Ns
//   l=7:    alpha = 256j,             Ns = 128,        N = 256
// Ping-pong LDS: bufE (even layers incl. staged y0, 132 rows), bufO (odd, 256).
// Out-of-range t (<0 or >=T_l) stored as zero (matches conv zero-pad).
// ---------------------------------------------------------------------------
__global__ __launch_bounds__(256) void mid_kernel(
    const unsigned short* __restrict__ y0g,
    const short* __restrict__ wfold, const float* __restrict__ nzu_b,
    const float* __restrict__ nzf_w, const float* __restrict__ nzf_b,
    const float* __restrict__ noise,
    const float* __restrict__ amp, const float* __restrict__ frq,
    const float* __restrict__ ph, float* __restrict__ out)
{
  __shared__ __align__(16) short bufE[132*72];
  __shared__ __align__(16) short bufO[256*72];
  __shared__ float al[1024], fqv[1024], pl[1024];
  __shared__ float wl[192];

  const int j   = blockIdx.x;
  const int b   = blockIdx.y;
  const int tid = threadIdx.x;
  const int L   = tid & 63;
  const int w   = tid >> 6;
  const int mt  = w & 1;
  const int ng  = w >> 1;          // 0 or 1

  // stage osc tables + nz_final weights
  for (int i = tid; i < 1024; i += 256) {
    al[i]  = amp[b*1024 + i];
    fqv[i] = frq[b*1024 + i];
    pl[i]  = ph[b*1024 + i];
  }
  if (tid < 192) { int o = tid >> 6, c = tid & 63; wl[c*3 + o] = nzf_w[tid]; }

  // stage y0 window: rows r<6, t = 2j-2+r (zeros outside [0,32))
  for (int i = tid; i < 48; i += 256) {
    int r = i >> 3, pos = (i & 7) << 3;
    int t = 2*j - 2 + r;
    bf16x8 v = {0,0,0,0,0,0,0,0};
    if (t >= 0 && t < 32) v = *(const bf16x8*)(y0g + (size_t)(b*32 + t)*64 + pos);
    *(bf16x8*)&bufE[r*72 + pos] = v;
  }
  __syncthreads();

  for (int l = 1; l <= 7; ++l) {
    const short* bin  = (l & 1) ? bufE : bufO;
    short*       bout = (l & 1) ? bufO : bufE;
    const int Ns    = (l == 7) ? 128 : (2 + (1 << l));
    const int Nin   = (l == 1) ? 6 : (2 * (2 + (1 << (l-1))));
    const int ntile = (Ns + 31) >> 5;
    const int aout  = (l == 7) ? 256*j : ((1 << (l+1))*j - 2);
    const int Tl    = 32 << l;
    const int off   = (l == 7) ? 2 : 1;
    const short* wf = wfold + (l-1)*16384;

    // A fragments + bias for this wave's m-half
    bf16x8 Af[4][4];
    {
      const short* wb = wf + (mt*32 + (L & 31))*64 + ((L >> 5) << 3);
      #pragma unroll
      for (int pd = 0; pd < 4; ++pd)
        #pragma unroll
        for (int ks = 0; ks < 4; ++ks)
          Af[pd][ks] = *(const bf16x8*)(wb + pd*4096 + ks*16);
    }
    f32x16 binit;
    #pragma unroll
    for (int r = 0; r < 16; ++r)
      binit[r] = nzu_b[(l-1)*64 + mt*32 + (r & 3) + 8*(r >> 2) + 4*(L >> 5)];

    for (int ti = ng; ti < ntile; ti += 2) {
      const int sl   = ti*32 + (L & 31);               // s' - s_alpha
      int slot = sl + off;
      slot = (slot > Nin - 2) ? (Nin - 2) : slot;       // clamp (invalid lanes)
      const short* bp = bin + slot*72 + ((L >> 5) << 3);
      f32x16 Ce = binit, Co = binit;
      #pragma unroll
      for (int ks = 0; ks < 4; ++ks) {
        bf16x8 Bm = *(const bf16x8*)(bp - 72 + ks*16);
        bf16x8 B0 = *(const bf16x8*)(bp + ks*16);
        bf16x8 Bp = *(const bf16x8*)(bp + 72 + ks*16);
        Ce = __builtin_amdgcn_mfma_f32_32x32x16_bf16(Af[0][ks], Bm, Ce, 0, 0, 0);
        Ce = __builtin_amdgcn_mfma_f32_32x32x16_bf16(Af[1][ks], B0, Ce, 0, 0, 0);
        Co = __builtin_amdgcn_mfma_f32_32x32x16_bf16(Af[2][ks], B0, Co, 0, 0, 0);
        Co = __builtin_amdgcn_mfma_f32_32x32x16_bf16(Af[3][ks], Bp, Co, 0, 0, 0);
      }
      if (sl < Ns) {
        const int te = aout + 2*sl;
        const bool ze = (te < 0) || (te >= Tl);
        const bool zo = (te + 1 < 0) || (te + 1 >= Tl);
        #pragma unroll
        for (int q4 = 0; q4 < 4; ++q4) {
          int co0 = mt*32 + 8*q4 + 4*(L >> 5);
          uint2 ve, vo;
          ve.x = ze ? 0u : pack2(lrelu(Ce[4*q4+0]), lrelu(Ce[4*q4+1]));
          ve.y = ze ? 0u : pack2(lrelu(Ce[4*q4+2]), lrelu(Ce[4*q4+3]));
          vo.x = zo ? 0u : pack2(lrelu(Co[4*q4+0]), lrelu(Co[4*q4+1]));
          vo.y = zo ? 0u : pack2(lrelu(Co[4*q4+2]), lrelu(Co[4*q4+3]));
          *(uint2*)&bout[(2*sl)*72 + co0]     = ve;
          *(uint2*)&bout[(2*sl + 1)*72 + co0] = vo;
        }
      }
    }
    __syncthreads();
  }

  // ---- epilogue: one thread per frame; y7 in bufO rows 0..255 ----
  {
    const short* yr = &bufO[tid * 72];
    float c0 = nzf_b[0], c1 = nzf_b[1], c2 = nzf_b[2];
    #pragma unroll
    for (int c8 = 0; c8 < 8; ++c8) {
      bf16x8 v = *(const bf16x8*)(yr + c8*8);
      #pragma unroll
      for (int jj = 0; jj < 8; ++jj) {
        float yv = bf2f((unsigned short)v[jj]);
        int c = c8*8 + jj;
        c0 = fmaf(wl[c*3+0], yv, c0);
        c1 = fmaf(wl[c*3+1], yv, c1);
        c2 = fmaf(wl[c*3+2], yv, c2);
      }
    }
    c0 *= c0; c1 *= c1; c2 *= c2;

    const int fb = 256*j + tid;                 // frame in [0,4096)
    const float4 n = *(const float4*)(noise + ((size_t)b*4096 + fb)*4);
    float F0  = c0 * (n.x + n.y + n.z + n.w) * 0.5f;
    float F1r = c1 * (n.x - n.z) * 0.5f;
    float F1i = -(c1 * (n.y - n.w) * 0.5f);
    float F2  = c2 * (n.x - n.y + n.z - n.w) * 0.5f;
    float r0 = 0.5f * (F0 + 2.f*F1r + F2);
    float r1 = 0.5f * (F0 - 2.f*F1i - F2);
    float r2 = 0.5f * (F0 - 2.f*F1r + F2);
    float r3 = 0.5f * (F0 + 2.f*F1i - F2);

    const int t0 = fb * 4;
    float s0a = 0.f, s1a = 0.f, s2a = 0.f, s3a = 0.f;
    if (t0 < 256) {
      const float tp = (float)(t0 + 1) * 0.5f;
      #pragma unroll 4
      for (int o = 0; o < 32; ++o) {
        float f0 = fqv[o*32], am = al[o*32];
        float hf = 0.5f * f0;
        float v0 = tp * f0, v1 = v0 + hf, v2 = v1 + hf, v3 = v2 + hf;
        s0a += am * sin_rev(v0 - floorf(v0));
        s1a += am * sin_rev(v1 - floorf(v1));
        s2a += am * sin_rev(v2 - floorf(v2));
        s3a += am * sin_rev(v3 - floorf(v3));
      }
    } else if (t0 >= 16128) {
      const float tp = (float)(t0 - 16127) * 0.5f;
      #pragma unroll 4
      for (int o = 0; o < 32; ++o) {
        float f0 = fqv[o*32 + 31], am = al[o*32 + 31], p = pl[o*32 + 31];
        float hf = 0.5f * f0;
        float v0 = p + tp * f0, v1 = v0 + hf, v2 = v1 + hf, v3 = v2 + hf;
        s0a += am * sin_rev(v0 - floorf(v0));
        s1a += am * sin_rev(v1 - floorf(v1));
        s2a += am * sin_rev(v2 - floorf(v2));
        s3a += am * sin_rev(v3 - floorf(v3));
      }
    } else {
      const int i  = (t0 - 256) >> 9;
      const int m0 = (t0 - 256) & 511;
      float mm[4], fa[4], mq[4];
      #pragma unroll
      for (int js = 0; js < 4; ++js) {
        float mmv = (float)(m0 + 1 + js);
        mm[js] = mmv;
        fa[js] = ((float)(m0 + js) + 0.5f) * (1.f/512.f);
        mq[js] = mmv * mmv * (1.f/1024.f);
      }
      #pragma unroll 4
      for (int o = 0; o < 32; ++o) {
        float f0 = fqv[o*32 + i], f1 = fqv[o*32 + i + 1];
        float a0 = al[o*32 + i],  a1 = al[o*32 + i + 1];
        float p  = pl[o*32 + i];
        float df = f1 - f0, da = a1 - a0;
        #pragma unroll
        for (int js = 0; js < 4; ++js) {
          float av   = fmaf(da, fa[js], a0);
          float part = fmaf(df, mq[js], mm[js] * f0);
          float v    = fmaf(part, 0.5f, p);
          float fr   = v - floorf(v);
          float sv   = av * sin_rev(fr);
          if      (js == 0) s0a += sv;
          else if (js == 1) s1a += sv;
          else if (js == 2) s2a += sv;
          else              s3a += sv;
        }
      }
    }
    float4 res = make_float4(s0a + r0, s1a + r1, s2a + r2, s3a + r3);
    *(float4*)(out + ((size_t)b*4096 + fb)*4) = res;
  }
}

// ---------------------------------------------------------------------------
extern "C" void kernel_launch(void* const* d_in, const int* in_sizes, int n_in,
                              void* d_out, int out_size, void* d_ws, size_t ws_size,
                              hipStream_t stream) {
  (void)in_sizes; (void)n_in; (void)out_size; (void)ws_size;
  const float* x     = (const float*)d_in[0];
  const float* noise = (const float*)d_in[1];
  const float* net_w = (const float*)d_in[2];
  const float* net_b = (const float*)d_in[3];
  const float* fin_w = (const float*)d_in[4];
  const float* fin_b = (const float*)d_in[5];
  const float* amp_w = (const float*)d_in[6];
  const float* amp_b = (const float*)d_in[7];
  const float* frq_w = (const float*)d_in[8];
  const float* frq_b = (const float*)d_in[9];
  const float* nzi_w = (const float*)d_in[10];
  const float* nzi_b = (const float*)d_in[11];
  const float* nzu_w = (const float*)d_in[12];
  const float* nzu_b = (const float*)d_in[13];
  const float* nzf_w = (const float*)d_in[14];
  const float* nzf_b = (const float*)d_in[15];
  float* out = (float*)d_out;

  // workspace (~1.3 MiB): y0g | wfold | amp | frq | ph
  short* y0g   = (short*)d_ws;                       // 64*32*64
  short* wfold = y0g + (size_t)64*32*64;             // 7*16384
  float* ampv  = (float*)(wfold + 7*16384);          // 65536
  float* frqv  = ampv + 65536;
  float* phv   = frqv + 65536;

  z_front<<<dim3(64), dim3(512), 0, stream>>>(
      x, net_w, net_b, fin_w, fin_b, amp_w, amp_b, frq_w, frq_b,
      nzi_w, nzi_b, nzu_w, (unsigned short*)y0g, wfold, ampv, frqv, phv);

  mid_kernel<<<dim3(16, 64), dim3(256), 0, stream>>>(
      (const unsigned short*)y0g, wfold, nzu_b, nzf_w, nzf_b, noise,
      ampv, frqv, phv, out);
}

// Round 8
// 223.939 us; speedup vs baseline: 1.1051x; 1.1051x over previous
//
#include <hip/hip_runtime.h>
#include <math.h>

// Problem constants
//  B=64, CH=64, T_IN=32, N_OSC=32, BAND=16384, N_NOISE_FRAMES=4096, NOISE_STEP=4
//  N_UP=7, LOWEST_FREQ = 20/11025
#define LOWEST_FREQ_F 0.00181405895691609977f

typedef short bf16x8 __attribute__((ext_vector_type(8)));
typedef float f32x16 __attribute__((ext_vector_type(16)));

__device__ __forceinline__ float lrelu(float x) { return x > 0.f ? x : 0.2f * x; }
__device__ __forceinline__ float sin_rev(float fr) { return __builtin_amdgcn_sinf(fr); }
__device__ __forceinline__ float bf2f(unsigned short u) {
  union { unsigned int i; float f; } x; x.i = ((unsigned int)u) << 16; return x.f;
}
__device__ __forceinline__ unsigned short f2bf(float f) {
  union { float f; unsigned int i; } x; x.f = f;
  unsigned int r = x.i + 0x7FFFu + ((x.i >> 16) & 1u);   // RNE
  return (unsigned short)(r >> 16);
}
__device__ __forceinline__ unsigned int pack2(float a, float b) {
  return (unsigned int)f2bf(a) | ((unsigned int)f2bf(b) << 16);
}

// ---------------------------------------------------------------------------
// In-LDS MFMA noise layer (even/odd folded up-conv + leaky), 8-wave version.
// A-fragments folded from RAW f32 weights into registers per-wave (no shared
// wfold dependency -> no cross-block race inside z_front).
// tin rows = sample+1 (halos 0 and TIN+1 zero), 64 cols, stride 72 shorts.
// v_mfma_f32_32x32x16_bf16 (HW-verified): A[m=L&31][k=(L>>5)*8+j],
// B[k][n=L&31], D col=L&31, row=(r&3)+8*(r>>2)+4*(L>>5).
// ---------------------------------------------------------------------------
template<int TIN>
__device__ __forceinline__ void noise_layer_raw(
    const short* tin, short* tout, const float* __restrict__ wraw,
    const float* __restrict__ bias, int tid)
{
  const int L  = tid & 63;
  const int w  = tid >> 6;
  const int mt = w & 1;
  const int ng = w >> 1;          // 0..3

  // fold A fragments directly from wraw[co*192 + ci*3 + k]
  bf16x8 Af[4][4];
  {
    const int co = mt*32 + (L & 31);
    const int kb = (L >> 5) << 3;
    #pragma unroll
    for (int ks = 0; ks < 4; ++ks) {
      #pragma unroll
      for (int j = 0; j < 8; ++j) {
        int ci = ks*16 + kb + j;
        const float* p = wraw + co*192 + ci*3;
        float w0 = p[0], w1 = p[1], w2 = p[2];
        Af[0][ks][j] = (short)f2bf(w0);
        Af[1][ks][j] = (short)f2bf(w1 + w2);
        Af[2][ks][j] = (short)f2bf(w0 + w1);
        Af[3][ks][j] = (short)f2bf(w2);
      }
    }
  }
  f32x16 binit;
  #pragma unroll
  for (int r = 0; r < 16; ++r)
    binit[r] = bias[mt*32 + (r & 3) + 8*(r >> 2) + 4*(L >> 5)];

  if (tid < 64) { tout[tid] = 0; tout[(2*TIN + 1)*72 + tid] = 0; }

  constexpr int TOT = TIN / 32;          // n-tiles total
  constexpr int NPG = (TOT + 3) / 4;     // n-tiles per ng group
  #pragma unroll
  for (int nt = 0; nt < NPG; ++nt) {
    int ntile = ng*NPG + nt;
    if (ntile < TOT) {
      int s = ntile*32 + (L & 31);
      const short* bp = tin + s*72 + ((L >> 5) << 3);   // row s = sample s-1
      f32x16 Ce = binit, Co = binit;
      #pragma unroll
      for (int ks = 0; ks < 4; ++ks) {
        bf16x8 Bm = *(const bf16x8*)(bp + ks*16);
        bf16x8 B0 = *(const bf16x8*)(bp + 72 + ks*16);
        bf16x8 Bp = *(const bf16x8*)(bp + 144 + ks*16);
        Ce = __builtin_amdgcn_mfma_f32_32x32x16_bf16(Af[0][ks], Bm, Ce, 0, 0, 0);
        Ce = __builtin_amdgcn_mfma_f32_32x32x16_bf16(Af[1][ks], B0, Ce, 0, 0, 0);
        Co = __builtin_amdgcn_mfma_f32_32x32x16_bf16(Af[2][ks], B0, Co, 0, 0, 0);
        Co = __builtin_amdgcn_mfma_f32_32x32x16_bf16(Af[3][ks], Bp, Co, 0, 0, 0);
      }
      #pragma unroll
      for (int q4 = 0; q4 < 4; ++q4) {
        int co0 = mt*32 + 8*q4 + 4*(L >> 5);
        uint2 ve, vo;
        ve.x = pack2(lrelu(Ce[4*q4+0]), lrelu(Ce[4*q4+1]));
        ve.y = pack2(lrelu(Ce[4*q4+2]), lrelu(Ce[4*q4+3]));
        vo.x = pack2(lrelu(Co[4*q4+0]), lrelu(Co[4*q4+1]));
        vo.y = pack2(lrelu(Co[4*q4+2]), lrelu(Co[4*q4+3]));
        *(uint2*)&tout[(2*s + 1)*72 + co0] = ve;
        *(uint2*)&tout[(2*s + 2)*72 + co0] = vo;
      }
    }
  }
  __syncthreads();
}

// ---------------------------------------------------------------------------
// z_front (round-4 structure, 512 threads, 1 block/batch):
//  - stages wfold layers 3..6 ONLY (consumed by LATER launches — cross-launch
//    ordering is safe; never read within this kernel)
//  - f32 conv stack, 8-wave layout, gather-prefetched weights
//  - nz_init -> y0 tile, amp/freq projections, fp64 phase prefix
//  - noise layers 0..2 in LDS (register-folded weights), write y3 [b][t][co]
// ---------------------------------------------------------------------------
__global__ __launch_bounds__(512) void z_front(
    const float* __restrict__ x,
    const float* __restrict__ net_w, const float* __restrict__ net_b,
    const float* __restrict__ fin_w, const float* __restrict__ fin_b,
    const float* __restrict__ amp_w, const float* __restrict__ amp_b,
    const float* __restrict__ frq_w, const float* __restrict__ frq_b,
    const float* __restrict__ nzi_w, const float* __restrict__ nzi_b,
    const float* __restrict__ nzu_w, const float* __restrict__ nzu_b,
    unsigned short* __restrict__ y3, short* __restrict__ wfold,
    float* __restrict__ amp_o, float* __restrict__ frq_o,
    float* __restrict__ ph_o)
{
  // arena: [tileB 258x72sh = 37152 | tileA 130x72sh = 18720]  (wbuf 12288 f32
  //        = 49152 B overlays tiles; dead before tiles used)
  //        za 9216 | zb 9216 | awL 8192 | fwL 8192 | nzL 16384 | fl 4224
  __shared__ __align__(16) char arena[111296];
  short* tileB = (short*)arena;
  short* tileA = (short*)(arena + 37152);
  float* wbuf  = (float*)arena;
  float* za    = (float*)(arena + 55872);
  float* zb    = (float*)(arena + 65088);
  float* awL   = (float*)(arena + 74304);
  float* fwL   = (float*)(arena + 82496);
  float* nzL   = (float*)(arena + 90688);
  float* fl    = (float*)(arena + 107072);

  const int b   = blockIdx.x;
  const int tid = threadIdx.x;
  const int co  = tid & 63;
  const int q   = tid >> 6;   // 0..7

  // ---- wfold slice for layers 3..6 (consumed by mid3/final launches) ----
  for (int i = tid; i < 1024; i += 512) {
    int g = 3*16384 + b*1024 + i;
    int l = g >> 14, qq = g & 16383;
    int pd = qq >> 12, coo = (qq >> 6) & 63, ci = qq & 63;
    const float* wb = nzu_w + l * 12288 + coo * 192 + ci * 3;
    float v;
    if      (pd == 0) v = wb[0];
    else if (pd == 1) v = wb[1] + wb[2];
    else if (pd == 2) v = wb[0] + wb[1];
    else              v = wb[2];
    wfold[g] = (short)f2bf(v);
  }

  // ---- stage input + small tables (gather transposes) ----
  for (int idx = tid; idx < 2048; idx += 512) {
    int t = idx >> 6, c = idx & 63;
    za[c*36 + t + 1] = x[b*2048 + idx];
  }
  if (tid < 64) {
    za[tid*36] = 0.f; za[tid*36 + 33] = 0.f;
    zb[tid*36] = 0.f; zb[tid*36 + 33] = 0.f;
  }
  for (int idx = tid; idx < 2048; idx += 512) {
    int o = idx & 31, c = idx >> 5;
    awL[idx] = amp_w[o*64 + c];      // awL[c*32+o]
    fwL[idx] = frq_w[o*64 + c];
  }
  for (int idx = tid; idx < 4096; idx += 512) {
    int o = idx & 63, c = idx >> 6;
    nzL[idx] = nzi_w[o*64 + c];      // nzL[c*64+o]
  }

  // ---- layer-0 weights: gather to registers then LDS [(ci*3+k)*64+co] ----
  float pr[24];
  #pragma unroll
  for (int k = 0; k < 8; ++k) {
    int idx = tid + 512*k;
    int ci = idx >> 6, c2 = idx & 63;
    const float* p = net_w + c2*192 + ci*3;
    pr[3*k+0] = p[0]; pr[3*k+1] = p[1]; pr[3*k+2] = p[2];
  }
  #pragma unroll
  for (int k = 0; k < 8; ++k) {
    int idx = tid + 512*k;
    int ci = idx >> 6, c2 = idx & 63;
    wbuf[(ci*3+0)*64 + c2] = pr[3*k+0];
    wbuf[(ci*3+1)*64 + c2] = pr[3*k+1];
    wbuf[(ci*3+2)*64 + c2] = pr[3*k+2];
  }
  __syncthreads();

  float* pa = za;
  float* pb = zb;
  for (int l = 0; l < 5; ++l) {
    if (l < 4) {   // prefetch next layer's weights into registers
      const float* src = (l+1 < 4) ? (net_w + (l+1)*12288) : fin_w;
      #pragma unroll
      for (int k = 0; k < 8; ++k) {
        int idx = tid + 512*k;
        int ci = idx >> 6, c2 = idx & 63;
        const float* p = src + c2*192 + ci*3;
        pr[3*k+0] = p[0]; pr[3*k+1] = p[1]; pr[3*k+2] = p[2];
      }
    }
    float acc[4];
    {
      float bv = (l < 4) ? net_b[l*64 + co] : fin_b[co];
      #pragma unroll
      for (int j = 0; j < 4; ++j) acc[j] = bv;
    }
    for (int ci = 0; ci < 64; ++ci) {
      const float* row = pa + ci*36 + q*4;
      float4 v0 = *(const float4*)(row);
      float4 v1 = *(const float4*)(row + 4);
      float rr[8] = {v0.x, v0.y, v0.z, v0.w, v1.x, v1.y, v1.z, v1.w};
      float w0 = wbuf[(ci*3+0)*64 + co];
      float w1 = wbuf[(ci*3+1)*64 + co];
      float w2 = wbuf[(ci*3+2)*64 + co];
      #pragma unroll
      for (int j = 0; j < 4; ++j) {
        acc[j] = fmaf(w0, rr[j],   acc[j]);
        acc[j] = fmaf(w1, rr[j+1], acc[j]);
        acc[j] = fmaf(w2, rr[j+2], acc[j]);
      }
    }
    const bool act = (l < 4);
    #pragma unroll
    for (int j = 0; j < 4; ++j) {
      float v = acc[j];
      pb[co*36 + q*4 + j + 1] = act ? lrelu(v) : v;
    }
    __syncthreads();
    if (l < 4) {
      #pragma unroll
      for (int k = 0; k < 8; ++k) {
        int idx = tid + 512*k;
        int ci = idx >> 6, c2 = idx & 63;
        wbuf[(ci*3+0)*64 + c2] = pr[3*k+0];
        wbuf[(ci*3+1)*64 + c2] = pr[3*k+1];
        wbuf[(ci*3+2)*64 + c2] = pr[3*k+2];
      }
      __syncthreads();
    }
    float* tp = pa; pa = pb; pb = tp;
  }
  const float* zf = pa;   // final z, 64 ch x 32 t (+pads)

  // ---- y0 = nz_init 1x1 conv (f32) -> bf16 into tileA rows t+1 ----
  {
    float acc[4];
    float bv = nzi_b[co];
    #pragma unroll
    for (int j = 0; j < 4; ++j) acc[j] = bv;
    #pragma unroll 8
    for (int c = 0; c < 64; ++c) {
      float wv = nzL[c*64 + co];
      const float* rw = zf + c*36 + q*4 + 1;
      #pragma unroll
      for (int j = 0; j < 4; ++j) acc[j] = fmaf(wv, rw[j], acc[j]);
    }
    #pragma unroll
    for (int j = 0; j < 4; ++j)
      tileA[(q*4 + j + 1)*72 + co] = (short)f2bf(acc[j]);
  }
  if (tid < 64) { tileA[tid] = 0; tileA[33*72 + tid] = 0; }

  // ---- amp / freq projections from LDS ----
  #pragma unroll
  for (int tt = 0; tt < 2; ++tt) {
    int task = tid + 512*tt;
    int o = task & 31, t = task >> 5;
    float aa = amp_b[o], ff = frq_b[o];
    #pragma unroll 8
    for (int c = 0; c < 64; ++c) {
      float zv = zf[c*36 + t + 1];
      aa = fmaf(awL[c*32 + o], zv, aa);
      ff = fmaf(fwL[c*32 + o], zv, ff);
    }
    aa = fabsf(aa);
    float sg = 1.f / (1.f + expf(-ff));
    float fq = LOWEST_FREQ_F + sg * (1.f - LOWEST_FREQ_F);
    amp_o[b*1024 + o*32 + t] = aa;
    frq_o[b*1024 + o*32 + t] = fq;
    fl[o*33 + t] = fq;
  }
  __syncthreads();

  // ---- fp64 phase boundary prefix: store frac(P[i]/2) ----
  if (tid < 32) {
    const int o = tid;
    double P = 256.0 * (double)fl[o*33];
    double h = P * 0.5;
    ph_o[b*1024 + o*32] = (float)(h - floor(h));
    for (int i = 1; i < 32; ++i) {
      P += 256.0 * ((double)fl[o*33 + i - 1] + (double)fl[o*33 + i]);
      h = P * 0.5;
      ph_o[b*1024 + o*32 + i] = (float)(h - floor(h));
    }
  }

  // ---- noise layers 0..2 in LDS: T 32 -> 64 -> 128 -> 256 ----
  noise_layer_raw<32> (tileA, tileB, nzu_w + 0*12288, nzu_b + 0*64, tid);
  noise_layer_raw<64> (tileB, tileA, nzu_w + 1*12288, nzu_b + 1*64, tid);
  noise_layer_raw<128>(tileA, tileB, nzu_w + 2*12288, nzu_b + 2*64, tid);

  // write y3 [b][t][co] (T=256), contiguous 16B chunks
  unsigned short* yb = y3 + (size_t)b * 16384;
  for (int c = tid; c < 2048; c += 512) {
    int row = c >> 3, pos = (c & 7) << 3;
    *(bf16x8*)(yb + c*8) = *(const bf16x8*)&tileB[(row + 1)*72 + pos];
  }
}

// ---------------------------------------------------------------------------
// mid3: layers 3,4,5 (y3 T=256 -> y6 T=2048) fused with halo recompute.
// Grid (8, 64): block = (k, b) covers y6 samples [256k, 256k+256).
// Windows: y3 [32k-2, 32k+34) 36 rows; y4 [64k-2, 64k+66) 68 rows;
//          y5 [128k-2, 128k+130) 132 rows; y6 written directly to global.
// Out-of-range rows stored as zero (matches conv zero-pad).
// ---------------------------------------------------------------------------
__global__ __launch_bounds__(256) void mid3_kernel(
    const unsigned short* __restrict__ y3, unsigned short* __restrict__ y6,
    const short* __restrict__ wfold, const float* __restrict__ nzu_b)
{
  __shared__ __align__(16) short bufI[36*72];    // y3 window, base 32k-2
  __shared__ __align__(16) short bufA[68*72];    // y4 window, base 64k-2
  __shared__ __align__(16) short bufB[132*72];   // y5 window, base 128k-2

  const int k   = blockIdx.x;
  const int b   = blockIdx.y;
  const int tid = threadIdx.x;
  const int L   = tid & 63;
  const int w   = tid >> 6;
  const int mt  = w & 1;
  const int ng  = w >> 1;   // 0 or 1

  // stage y3 window (zero-padded)
  const unsigned short* inb = y3 + (size_t)b * 256 * 64;
  for (int i = tid; i < 36*8; i += 256) {
    int r = i >> 3, pos = (i & 7) << 3;
    int t = 32*k - 2 + r;
    bf16x8 v = {0,0,0,0,0,0,0,0};
    if (t >= 0 && t < 256) v = *(const bf16x8*)(inb + (size_t)t*64 + pos);
    *(bf16x8*)&bufI[r*72 + pos] = v;
  }
  __syncthreads();

  unsigned short* outb = y6 + (size_t)b * 2048 * 64;

  for (int l = 0; l < 3; ++l) {
    const short* bin  = (l == 0) ? bufI : (l == 1) ? bufA : bufB;
    short*       bout = (l == 0) ? bufA : bufB;       // l==2 -> global
    const int cnt   = (l == 0) ? 34 : (l == 1) ? 66 : 128;
    const int croff = (l == 2) ? 2 : 1;
    const int tb    = (l == 0) ? (64*k - 2) : (128*k - 2);
    const int Tl    = (l == 0) ? 512 : 1024;
    const short* wf   = wfold + (3 + l)*16384;
    const float* bias = nzu_b + (3 + l)*64;

    bf16x8 Af[4][4];
    {
      const short* wb = wf + (mt*32 + (L & 31))*64 + ((L >> 5) << 3);
      #pragma unroll
      for (int pd = 0; pd < 4; ++pd)
        #pragma unroll
        for (int ks = 0; ks < 4; ++ks)
          Af[pd][ks] = *(const bf16x8*)(wb + pd*4096 + ks*16);
    }
    f32x16 binit;
    #pragma unroll
    for (int r = 0; r < 16; ++r)
      binit[r] = bias[mt*32 + (r & 3) + 8*(r >> 2) + 4*(L >> 5)];

    for (int ti = ng; ti*32 < cnt; ti += 2) {
      const int sl  = ti*32 + (L & 31);
      const int slc = (sl < cnt) ? sl : (cnt - 1);
      const short* bp = bin + (slc + croff)*72 + ((L >> 5) << 3);
      f32x16 Ce = binit, Co = binit;
      #pragma unroll
      for (int ks = 0; ks < 4; ++ks) {
        bf16x8 Bm = *(const bf16x8*)(bp - 72 + ks*16);
        bf16x8 B0 = *(const bf16x8*)(bp + ks*16);
        bf16x8 Bp = *(const bf16x8*)(bp + 72 + ks*16);
        Ce = __builtin_amdgcn_mfma_f32_32x32x16_bf16(Af[0][ks], Bm, Ce, 0, 0, 0);
        Ce = __builtin_amdgcn_mfma_f32_32x32x16_bf16(Af[1][ks], B0, Ce, 0, 0, 0);
        Co = __builtin_amdgcn_mfma_f32_32x32x16_bf16(Af[2][ks], B0, Co, 0, 0, 0);
        Co = __builtin_amdgcn_mfma_f32_32x32x16_bf16(Af[3][ks], Bp, Co, 0, 0, 0);
      }
      if (sl < cnt) {
        if (l < 2) {
          const int te = tb + 2*sl;
          const bool ze = (te < 0) || (te >= Tl);
          const bool zo = (te + 1 < 0) || (te + 1 >= Tl);
          #pragma unroll
          for (int q4 = 0; q4 < 4; ++q4) {
            int co0 = mt*32 + 8*q4 + 4*(L >> 5);
            uint2 ve, vo;
            ve.x = ze ? 0u : pack2(lrelu(Ce[4*q4+0]), lrelu(Ce[4*q4+1]));
            ve.y = ze ? 0u : pack2(lrelu(Ce[4*q4+2]), lrelu(Ce[4*q4+3]));
            vo.x = zo ? 0u : pack2(lrelu(Co[4*q4+0]), lrelu(Co[4*q4+1]));
            vo.y = zo ? 0u : pack2(lrelu(Co[4*q4+2]), lrelu(Co[4*q4+3]));
            *(uint2*)&bout[(2*sl)*72 + co0]     = ve;
            *(uint2*)&bout[(2*sl + 1)*72 + co0] = vo;
          }
        } else {
          const int t = 2*(128*k + sl);
          #pragma unroll
          for (int q4 = 0; q4 < 4; ++q4) {
            int co0 = mt*32 + 8*q4 + 4*(L >> 5);
            uint2 ve, vo;
            ve.x = pack2(lrelu(Ce[4*q4+0]), lrelu(Ce[4*q4+1]));
            ve.y = pack2(lrelu(Ce[4*q4+2]), lrelu(Ce[4*q4+3]));
            vo.x = pack2(lrelu(Co[4*q4+0]), lrelu(Co[4*q4+1]));
            vo.y = pack2(lrelu(Co[4*q4+2]), lrelu(Co[4*q4+3]));
            *(uint2*)(outb + (size_t)t*64 + co0)     = ve;
            *(uint2*)(outb + (size_t)(t+1)*64 + co0) = vo;
          }
        }
      }
    }
    __syncthreads();
  }
}

// ---------------------------------------------------------------------------
// Final fused: layer 6 (Tin=2048 -> 4096, y7 stays in LDS) + nz_final coeffs
// + squared + length-4 ortho rfft/irfft filter + oscillator bank.
// ---------------------------------------------------------------------------
__global__ __launch_bounds__(256) void final_fused(
    const unsigned short* __restrict__ in,    // y6 [b][t][co], Tin=2048
    const short* __restrict__ wf, const float* __restrict__ bias,
    const float* __restrict__ nzf_w, const float* __restrict__ nzf_b,
    const float* __restrict__ noise,
    const float* __restrict__ amp, const float* __restrict__ frq,
    const float* __restrict__ ph, float* __restrict__ out)
{
  constexpr int STILE = 128, Tin = 2048, ROWS = STILE + 2, G = STILE / 64;
  __shared__ __align__(16) short lB[ROWS * 72];     // 18720 B
  __shared__ __align__(16) short yT[256 * 72];      // 36864 B
  __shared__ float al[1024], fqv[1024], pl[1024];   // 12288 B
  __shared__ float wl[192];

  const int b   = blockIdx.y;
  const int s0  = blockIdx.x * STILE;
  const int tid = threadIdx.x;
  const int L   = tid & 63;
  const int w   = tid >> 6;
  const int mt  = w & 1;
  const int ng  = w >> 1;

  for (int i = tid; i < 1024; i += 256) {
    al[i]  = amp[b*1024 + i];
    fqv[i] = frq[b*1024 + i];
    pl[i]  = ph[b*1024 + i];
  }
  if (tid < 192) { int o = tid >> 6, c = tid & 63; wl[c*3 + o] = nzf_w[tid]; }

  bf16x8 Af[4][4];
  {
    const short* wb = wf + (mt*32 + (L & 31))*64 + ((L >> 5) << 3);
    #pragma unroll
    for (int pd = 0; pd < 4; ++pd)
      #pragma unroll
      for (int ks = 0; ks < 4; ++ks)
        Af[pd][ks] = *(const bf16x8*)(wb + pd*4096 + ks*16);
  }

  const unsigned short* inb = in + (size_t)b * Tin * 64;
  for (int c = tid; c < ROWS*8; c += 256) {
    int row = c >> 3, pos = (c & 7) << 3;
    int g = s0 - 1 + row;
    bf16x8 v = {0,0,0,0,0,0,0,0};
    if (g >= 0 && g < Tin) v = *(const bf16x8*)(inb + (size_t)g*64 + pos);
    *(bf16x8*)&lB[row*72 + pos] = v;
  }

  f32x16 binit;
  #pragma unroll
  for (int r = 0; r < 16; ++r)
    binit[r] = bias[mt*32 + (r & 3) + 8*(r >> 2) + 4*(L >> 5)];

  __syncthreads();

  #pragma unroll
  for (int nt = 0; nt < G; ++nt) {
    int s_loc = ng*(32*G) + nt*32 + (L & 31);
    const short* bp = lB + s_loc*72 + ((L >> 5) << 3);
    f32x16 Ce = binit, Co = binit;
    #pragma unroll
    for (int ks = 0; ks < 4; ++ks) {
      bf16x8 Bm = *(const bf16x8*)(bp + ks*16);
      bf16x8 B0 = *(const bf16x8*)(bp + 72 + ks*16);
      bf16x8 Bp = *(const bf16x8*)(bp + 144 + ks*16);
      Ce = __builtin_amdgcn_mfma_f32_32x32x16_bf16(Af[0][ks], Bm, Ce, 0, 0, 0);
      Ce = __builtin_amdgcn_mfma_f32_32x32x16_bf16(Af[1][ks], B0, Ce, 0, 0, 0);
      Co = __builtin_amdgcn_mfma_f32_32x32x16_bf16(Af[2][ks], B0, Co, 0, 0, 0);
      Co = __builtin_amdgcn_mfma_f32_32x32x16_bf16(Af[3][ks], Bp, Co, 0, 0, 0);
    }
    #pragma unroll
    for (int q4 = 0; q4 < 4; ++q4) {
      int co0 = mt*32 + 8*q4 + 4*(L >> 5);
      uint2 ve, vo;
      ve.x = pack2(lrelu(Ce[4*q4+0]), lrelu(Ce[4*q4+1]));
      ve.y = pack2(lrelu(Ce[4*q4+2]), lrelu(Ce[4*q4+3]));
      vo.x = pack2(lrelu(Co[4*q4+0]), lrelu(Co[4*q4+1]));
      vo.y = pack2(lrelu(Co[4*q4+2]), lrelu(Co[4*q4+3]));
      *(uint2*)&yT[(2*s_loc)*72 + co0]     = ve;
      *(uint2*)&yT[(2*s_loc + 1)*72 + co0] = vo;
    }
  }
  __syncthreads();

  // epilogue: one thread per frame (local t = tid)
  {
    const short* yr = &yT[tid * 72];
    float c0 = nzf_b[0], c1 = nzf_b[1], c2 = nzf_b[2];
    #pragma unroll
    for (int c8 = 0; c8 < 8; ++c8) {
      bf16x8 v = *(const bf16x8*)(yr + c8*8);
      #pragma unroll
      for (int jj = 0; jj < 8; ++jj) {
        float yv = bf2f((unsigned short)v[jj]);
        int c = c8*8 + jj;
        c0 = fmaf(wl[c*3+0], yv, c0);
        c1 = fmaf(wl[c*3+1], yv, c1);
        c2 = fmaf(wl[c*3+2], yv, c2);
      }
    }
    c0 *= c0; c1 *= c1; c2 *= c2;

    const int fb = 2*s0 + tid;                 // frame in [0,4096)
    const float4 n = *(const float4*)(noise + ((size_t)b*4096 + fb)*4);
    float F0  = c0 * (n.x + n.y + n.z + n.w) * 0.5f;
    float F1r = c1 * (n.x - n.z) * 0.5f;
    float F1i = -(c1 * (n.y - n.w) * 0.5f);
    float F2  = c2 * (n.x - n.y + n.z - n.w) * 0.5f;
    float r0 = 0.5f * (F0 + 2.f*F1r + F2);
    float r1 = 0.5f * (F0 - 2.f*F1i - F2);
    float r2 = 0.5f * (F0 - 2.f*F1r + F2);
    float r3 = 0.5f * (F0 + 2.f*F1i - F2);

    const int t0 = fb * 4;
    float s0a = 0.f, s1a = 0.f, s2a = 0.f, s3a = 0.f;
    if (t0 < 256) {
      const float tp = (float)(t0 + 1) * 0.5f;
      #pragma unroll 4
      for (int o = 0; o < 32; ++o) {
        float f0 = fqv[o*32], am = al[o*32];
        float hf = 0.5f * f0;
        float v0 = tp * f0, v1 = v0 + hf, v2 = v1 + hf, v3 = v2 + hf;
        s0a += am * sin_rev(v0 - floorf(v0));
        s1a += am * sin_rev(v1 - floorf(v1));
        s2a += am * sin_rev(v2 - floorf(v2));
        s3a += am * sin_rev(v3 - floorf(v3));
      }
    } else if (t0 >= 16128) {
      const float tp = (float)(t0 - 16127) * 0.5f;
      #pragma unroll 4
      for (int o = 0; o < 32; ++o) {
        float f0 = fqv[o*32 + 31], am = al[o*32 + 31], p = pl[o*32 + 31];
        float hf = 0.5f * f0;
        float v0 = p + tp * f0, v1 = v0 + hf, v2 = v1 + hf, v3 = v2 + hf;
        s0a += am * sin_rev(v0 - floorf(v0));
        s1a += am * sin_rev(v1 - floorf(v1));
        s2a += am * sin_rev(v2 - floorf(v2));
        s3a += am * sin_rev(v3 - floorf(v3));
      }
    } else {
      const int i  = (t0 - 256) >> 9;
      const int m0 = (t0 - 256) & 511;
      float mm[4], fa[4], mq[4];
      #pragma unroll
      for (int js = 0; js < 4; ++js) {
        float mmv = (float)(m0 + 1 + js);
        mm[js] = mmv;
        fa[js] = ((float)(m0 + js) + 0.5f) * (1.f/512.f);
        mq[js] = mmv * mmv * (1.f/1024.f);
      }
      #pragma unroll 4
      for (int o = 0; o < 32; ++o) {
        float f0 = fqv[o*32 + i], f1 = fqv[o*32 + i + 1];
        float a0 = al[o*32 + i],  a1 = al[o*32 + i + 1];
        float p  = pl[o*32 + i];
        float df = f1 - f0, da = a1 - a0;
        #pragma unroll
        for (int js = 0; js < 4; ++js) {
          float av   = fmaf(da, fa[js], a0);
          float part = fmaf(df, mq[js], mm[js] * f0);
          float v    = fmaf(part, 0.5f, p);
          float fr   = v - floorf(v);
          float sv   = av * sin_rev(fr);
          if      (js == 0) s0a += sv;
          else if (js == 1) s1a += sv;
          else if (js == 2) s2a += sv;
          else              s3a += sv;
        }
      }
    }
    float4 res = make_float4(s0a + r0, s1a + r1, s2a + r2, s3a + r3);
    *(float4*)(out + ((size_t)b*4096 + fb)*4) = res;
  }
}

// ---------------------------------------------------------------------------
extern "C" void kernel_launch(void* const* d_in, const int* in_sizes, int n_in,
                              void* d_out, int out_size, void* d_ws, size_t ws_size,
                              hipStream_t stream) {
  (void)in_sizes; (void)n_in; (void)out_size; (void)ws_size;
  const float* x     = (const float*)d_in[0];
  const float* noise = (const float*)d_in[1];
  const float* net_w = (const float*)d_in[2];
  const float* net_b = (const float*)d_in[3];
  const float* fin_w = (const float*)d_in[4];
  const float* fin_b = (const float*)d_in[5];
  const float* amp_w = (const float*)d_in[6];
  const float* amp_b = (const float*)d_in[7];
  const float* frq_w = (const float*)d_in[8];
  const float* frq_b = (const float*)d_in[9];
  const float* nzi_w = (const float*)d_in[10];
  const float* nzi_b = (const float*)d_in[11];
  const float* nzu_w = (const float*)d_in[12];
  const float* nzu_b = (const float*)d_in[13];
  const float* nzf_w = (const float*)d_in[14];
  const float* nzf_b = (const float*)d_in[15];
  float* out = (float*)d_out;

  // workspace (~19 MiB): y3 | y6 | wfold | amp | frq | ph
  short* y3    = (short*)d_ws;                       // 64*256*64
  short* y6    = y3 + (size_t)64*256*64;             // 64*2048*64
  short* wfold = y6 + (size_t)64*2048*64;            // 7*16384 (layers 3..6 used)
  float* ampv  = (float*)(wfold + 7*16384);          // 65536
  float* frqv  = ampv + 65536;
  float* phv   = frqv + 65536;

  z_front<<<dim3(64), dim3(512), 0, stream>>>(
      x, net_w, net_b, fin_w, fin_b, amp_w, amp_b, frq_w, frq_b,
      nzi_w, nzi_b, nzu_w, nzu_b, (unsigned short*)y3, wfold,
      ampv, frqv, phv);

  mid3_kernel<<<dim3(8, 64), dim3(256), 0, stream>>>(
      (const unsigned short*)y3, (unsigned short*)y6, wfold, nzu_b);

  final_fused<<<dim3(16, 64), dim3(256), 0, stream>>>(
      (const unsigned short*)y6, wfold + 6*16384, nzu_b + 6*64,
      nzf_w, nzf_b, noise, ampv, frqv, phv, out);
}